// Round 2
// baseline (759.629 us; speedup 1.0000x reference)
//
#include <hip/hip_runtime.h>
#include <hip/hip_bf16.h>

#define N_NODES 10000
#define N_EDGES 320000
#define D 128
#define H 512

typedef __bf16 bf16x8 __attribute__((ext_vector_type(8)));
typedef float f32x4 __attribute__((ext_vector_type(4)));
typedef unsigned short u16x8 __attribute__((ext_vector_type(8)));

__device__ __forceinline__ unsigned short f2bf(float f) {
    union { float f; unsigned u; } v; v.f = f;
    unsigned r = v.u + 0x7fffu + ((v.u >> 16) & 1u);
    return (unsigned short)(r >> 16);
}

// ---------------- fused precompute: cast x, zero agg, swizzle 4 weights ----------------
// swizzle layout: [(kt*(N/16)+nt)*64 + lane]*8 bf16, elem j = W[kt*32+(lane>>4)*8+j][nt*16+(lane&15)]
__device__ __forceinline__ void swz(const float* __restrict__ W, unsigned short* __restrict__ out,
                                    int K, int Nn, int t) {
    int lane = t & 63;
    int tile = t >> 6;
    int ntiles = Nn >> 4;
    int nt = tile % ntiles;
    int kt = tile / ntiles;
    int k0 = kt * 32 + (lane >> 4) * 8;
    int n  = nt * 16 + (lane & 15);
    unsigned short tmp[8];
#pragma unroll
    for (int j = 0; j < 8; ++j) tmp[j] = f2bf(W[(size_t)(k0 + j) * Nn + n]);
    ushort4* dst = reinterpret_cast<ushort4*>(out + (size_t)t * 8);
    dst[0] = *reinterpret_cast<ushort4*>(&tmp[0]);
    dst[1] = *reinterpret_cast<ushort4*>(&tmp[4]);
}

__global__ __launch_bounds__(256) void precompute_kernel(
    const float* __restrict__ x, unsigned short* __restrict__ xb,
    const float* __restrict__ We1, unsigned short* __restrict__ We1s,
    const float* __restrict__ We2, unsigned short* __restrict__ We2s,
    const float* __restrict__ Wn1, unsigned short* __restrict__ Wn1s,
    const float* __restrict__ Wn2, unsigned short* __restrict__ Wn2s,
    float* __restrict__ agg)
{
    int b = blockIdx.x, tid = threadIdx.x;
    if (b < 1250) {                       // cast x -> bf16, 320000 ushort4
        int t = b * 256 + tid;
        float4 v = reinterpret_cast<const float4*>(x)[t];
        ushort4 o;
        o.x = f2bf(v.x); o.y = f2bf(v.y); o.z = f2bf(v.z); o.w = f2bf(v.w);
        reinterpret_cast<ushort4*>(xb)[t] = o;
    } else if (b < 2500) {                // zero agg, 320000 float4
        int t = (b - 1250) * 256 + tid;
        reinterpret_cast<float4*>(agg)[t] = (float4){0.f, 0.f, 0.f, 0.f};
    } else if (b < 2596) {                // We1 384x512 -> 96 blocks
        swz(We1, We1s, 384, 512, (b - 2500) * 256 + tid);
    } else if (b < 2628) {                // We2 512x128 -> 32 blocks
        swz(We2, We2s, 512, 128, (b - 2596) * 256 + tid);
    } else if (b < 2692) {                // Wn1 256x512 -> 64 blocks
        swz(Wn1, Wn1s, 256, 512, (b - 2628) * 256 + tid);
    } else {                              // Wn2 512x128 -> 32 blocks
        swz(Wn2, Wn2s, 512, 128, (b - 2692) * 256 + tid);
    }
}

// ---------------- fused edge MLP + scatter ----------------
// 64 edges/block, 4 waves. GEMM1 acc fully register-resident (wave w owns H-cols
// w*128..w*128+127 -> 8 ntiles x 4 mtiles = 128 VGPR acc). 3 barriers per block.
// sA: [64][384+8] bf16 (stride 49x16B, 49%8==1 -> conflict-free b128 reads)
// sH: [64][512+8] bf16 overlays sA after GEMM1 (stride 65x16B, 65%8==1)
__global__ __launch_bounds__(256, 2) void edge_mlp_kernel(
    const unsigned short* __restrict__ xb,
    const int* __restrict__ eidx,
    const float* __restrict__ edge_attr,
    const unsigned short* __restrict__ We1s,
    const float* __restrict__ be1,
    const unsigned short* __restrict__ We2s,
    const float* __restrict__ be2,
    float* __restrict__ out_edges,
    float* __restrict__ agg)
{
    __shared__ unsigned short smem[64 * 520];   // 66,560 B

    const int tid = threadIdx.x;
    const int wave = tid >> 6, lane = tid & 63;
    const int l15 = lane & 15, quad = lane >> 4;
    const int q8 = quad * 8;
    const int e0 = blockIdx.x * 64;

    // ---- stage A = concat(xb[s], xb[r], bf16(edge_attr)), stride 392 ----
#pragma unroll
    for (int seg = 0; seg < 2; ++seg) {
        for (int c = tid; c < 1024; c += 256) {
            int row = c >> 4;
            int off = (c & 15) << 3;
            int node = eidx[seg * N_EDGES + e0 + row];
            *reinterpret_cast<bf16x8*>(&smem[row * 392 + seg * 128 + off]) =
                *reinterpret_cast<const bf16x8*>(&xb[(size_t)node * 128 + off]);
        }
    }
    for (int c = tid; c < 1024; c += 256) {
        int row = c >> 4;
        int off = (c & 15) << 3;
        const float4* src = reinterpret_cast<const float4*>(&edge_attr[((size_t)(e0 + row)) * 128 + off]);
        float4 v0 = src[0], v1 = src[1];
        u16x8 o;
        o[0] = f2bf(v0.x); o[1] = f2bf(v0.y); o[2] = f2bf(v0.z); o[3] = f2bf(v0.w);
        o[4] = f2bf(v1.x); o[5] = f2bf(v1.y); o[6] = f2bf(v1.z); o[7] = f2bf(v1.w);
        *reinterpret_cast<u16x8*>(&smem[row * 392 + 256 + off]) = o;
    }
    __syncthreads();

    // ---- GEMM1: [64,384] @ We1[384,512], acc in registers ----
    f32x4 acc1[8][4];
#pragma unroll
    for (int nn = 0; nn < 8; ++nn)
#pragma unroll
        for (int mt = 0; mt < 4; ++mt) acc1[nn][mt] = (f32x4){0.f, 0.f, 0.f, 0.f};

#pragma unroll 2
    for (int kt = 0; kt < 12; ++kt) {
        bf16x8 a[4];
#pragma unroll
        for (int mt = 0; mt < 4; ++mt)
            a[mt] = *reinterpret_cast<const bf16x8*>(&smem[(mt * 16 + l15) * 392 + kt * 32 + q8]);
#pragma unroll
        for (int nn = 0; nn < 8; ++nn) {
            bf16x8 b = *reinterpret_cast<const bf16x8*>(
                &We1s[(((size_t)kt * 32 + wave * 8 + nn) * 64 + lane) * 8]);
#pragma unroll
            for (int mt = 0; mt < 4; ++mt)
                acc1[nn][mt] = __builtin_amdgcn_mfma_f32_16x16x32_bf16(a[mt], b, acc1[nn][mt], 0, 0, 0);
        }
    }
    __syncthreads();   // all sA reads done; safe to overlay with sH

    // ---- hidden = relu(acc1 + be1) -> bf16 sH, pair-packed b32 writes ----
    const int rs = (lane & 1) * 2;    // even lanes write r=0,1; odd write r=2,3
#pragma unroll
    for (int nn = 0; nn < 8; ++nn) {
        int cc = wave * 128 + nn * 16 + l15;
        float bias = be1[cc];
        int cp = cc & ~1;
#pragma unroll
        for (int mt = 0; mt < 4; ++mt) {
            float v[4], p[4];
#pragma unroll
            for (int r = 0; r < 4; ++r) {
                float t = acc1[nn][mt][r] + bias;
                v[r] = t > 0.f ? t : 0.f;
            }
#pragma unroll
            for (int r = 0; r < 4; ++r) p[r] = __shfl_xor(v[r], 1, 64);
#pragma unroll
            for (int r2 = 0; r2 < 2; ++r2) {
                int r = rs + r2;
                float lo = (lane & 1) ? p[r] : v[r];
                float hi = (lane & 1) ? v[r] : p[r];
                unsigned d = (unsigned)f2bf(lo) | ((unsigned)f2bf(hi) << 16);
                int row = mt * 16 + quad * 4 + r;
                *reinterpret_cast<unsigned*>(&smem[row * 520 + cp]) = d;
            }
        }
    }
    __syncthreads();

    // ---- GEMM2: [64,512] @ We2[512,128] ----
    f32x4 acc2[2][4];
#pragma unroll
    for (int nn = 0; nn < 2; ++nn)
#pragma unroll
        for (int mt = 0; mt < 4; ++mt) acc2[nn][mt] = (f32x4){0.f, 0.f, 0.f, 0.f};

#pragma unroll 2
    for (int kt = 0; kt < 16; ++kt) {
        bf16x8 a[4];
#pragma unroll
        for (int mt = 0; mt < 4; ++mt)
            a[mt] = *reinterpret_cast<const bf16x8*>(&smem[(mt * 16 + l15) * 520 + kt * 32 + q8]);
#pragma unroll
        for (int nn = 0; nn < 2; ++nn) {
            bf16x8 b = *reinterpret_cast<const bf16x8*>(
                &We2s[(((size_t)kt * 8 + wave * 2 + nn) * 64 + lane) * 8]);
#pragma unroll
            for (int mt = 0; mt < 4; ++mt)
                acc2[nn][mt] = __builtin_amdgcn_mfma_f32_16x16x32_bf16(a[mt], b, acc2[nn][mt], 0, 0, 0);
        }
    }

    // ---- epilogue: edge output + atomic scatter ----
    float bias2[2] = { be2[wave * 32 + l15], be2[wave * 32 + 16 + l15] };
#pragma unroll
    for (int mt = 0; mt < 4; ++mt) {
#pragma unroll
        for (int r = 0; r < 4; ++r) {
            int row = mt * 16 + quad * 4 + r;
            int e = e0 + row;
            int recv = eidx[N_EDGES + e];
#pragma unroll
            for (int nn = 0; nn < 2; ++nn) {
                int cc = wave * 32 + nn * 16 + l15;
                float v = acc2[nn][mt][r] + bias2[nn];
                out_edges[(size_t)e * 128 + cc] = v;
                atomicAdd(&agg[(size_t)recv * 128 + cc], v);
            }
        }
    }
}

// ---------------- fused node MLP ----------------
__global__ __launch_bounds__(256, 2) void node_mlp_kernel(
    const unsigned short* __restrict__ xb,
    const float* __restrict__ agg,
    const unsigned short* __restrict__ Wn1s,
    const float* __restrict__ bn1,
    const unsigned short* __restrict__ Wn2s,
    const float* __restrict__ bn2,
    float* __restrict__ out_nodes)
{
    __shared__ unsigned short smem[64 * 520];

    const int tid = threadIdx.x;
    const int wave = tid >> 6, lane = tid & 63;
    const int l15 = lane & 15, quad = lane >> 4;
    const int q8 = quad * 8;
    const int n0 = blockIdx.x * 64;

    // stage A = concat(xb, bf16(agg)), stride 264
    for (int c = tid; c < 1024; c += 256) {
        int row = c >> 4;
        int off = (c & 15) << 3;
        int node = n0 + row;
        bf16x8 v = {};
        if (node < N_NODES)
            v = *reinterpret_cast<const bf16x8*>(&xb[(size_t)node * 128 + off]);
        *reinterpret_cast<bf16x8*>(&smem[row * 264 + off]) = v;
    }
    for (int c = tid; c < 1024; c += 256) {
        int row = c >> 4;
        int off = (c & 15) << 3;
        int node = n0 + row;
        u16x8 o = {0, 0, 0, 0, 0, 0, 0, 0};
        if (node < N_NODES) {
            const float4* src = reinterpret_cast<const float4*>(&agg[(size_t)node * 128 + off]);
            float4 v0 = src[0], v1 = src[1];
            o[0] = f2bf(v0.x); o[1] = f2bf(v0.y); o[2] = f2bf(v0.z); o[3] = f2bf(v0.w);
            o[4] = f2bf(v1.x); o[5] = f2bf(v1.y); o[6] = f2bf(v1.z); o[7] = f2bf(v1.w);
        }
        *reinterpret_cast<u16x8*>(&smem[row * 264 + 128 + off]) = o;
    }
    __syncthreads();

    // GEMM1: [64,256] @ Wn1[256,512], register acc
    f32x4 acc1[8][4];
#pragma unroll
    for (int nn = 0; nn < 8; ++nn)
#pragma unroll
        for (int mt = 0; mt < 4; ++mt) acc1[nn][mt] = (f32x4){0.f, 0.f, 0.f, 0.f};

#pragma unroll 2
    for (int kt = 0; kt < 8; ++kt) {
        bf16x8 a[4];
#pragma unroll
        for (int mt = 0; mt < 4; ++mt)
            a[mt] = *reinterpret_cast<const bf16x8*>(&smem[(mt * 16 + l15) * 264 + kt * 32 + q8]);
#pragma unroll
        for (int nn = 0; nn < 8; ++nn) {
            bf16x8 b = *reinterpret_cast<const bf16x8*>(
                &Wn1s[(((size_t)kt * 32 + wave * 8 + nn) * 64 + lane) * 8]);
#pragma unroll
            for (int mt = 0; mt < 4; ++mt)
                acc1[nn][mt] = __builtin_amdgcn_mfma_f32_16x16x32_bf16(a[mt], b, acc1[nn][mt], 0, 0, 0);
        }
    }
    __syncthreads();

    const int rs = (lane & 1) * 2;
#pragma unroll
    for (int nn = 0; nn < 8; ++nn) {
        int cc = wave * 128 + nn * 16 + l15;
        float bias = bn1[cc];
        int cp = cc & ~1;
#pragma unroll
        for (int mt = 0; mt < 4; ++mt) {
            float v[4], p[4];
#pragma unroll
            for (int r = 0; r < 4; ++r) {
                float t = acc1[nn][mt][r] + bias;
                v[r] = t > 0.f ? t : 0.f;
            }
#pragma unroll
            for (int r = 0; r < 4; ++r) p[r] = __shfl_xor(v[r], 1, 64);
#pragma unroll
            for (int r2 = 0; r2 < 2; ++r2) {
                int r = rs + r2;
                float lo = (lane & 1) ? p[r] : v[r];
                float hi = (lane & 1) ? v[r] : p[r];
                unsigned d = (unsigned)f2bf(lo) | ((unsigned)f2bf(hi) << 16);
                int row = mt * 16 + quad * 4 + r;
                *reinterpret_cast<unsigned*>(&smem[row * 520 + cp]) = d;
            }
        }
    }
    __syncthreads();

    f32x4 acc2[2][4];
#pragma unroll
    for (int nn = 0; nn < 2; ++nn)
#pragma unroll
        for (int mt = 0; mt < 4; ++mt) acc2[nn][mt] = (f32x4){0.f, 0.f, 0.f, 0.f};

#pragma unroll 2
    for (int kt = 0; kt < 16; ++kt) {
        bf16x8 a[4];
#pragma unroll
        for (int mt = 0; mt < 4; ++mt)
            a[mt] = *reinterpret_cast<const bf16x8*>(&smem[(mt * 16 + l15) * 520 + kt * 32 + q8]);
#pragma unroll
        for (int nn = 0; nn < 2; ++nn) {
            bf16x8 b = *reinterpret_cast<const bf16x8*>(
                &Wn2s[(((size_t)kt * 8 + wave * 2 + nn) * 64 + lane) * 8]);
#pragma unroll
            for (int mt = 0; mt < 4; ++mt)
                acc2[nn][mt] = __builtin_amdgcn_mfma_f32_16x16x32_bf16(a[mt], b, acc2[nn][mt], 0, 0, 0);
        }
    }

    float bias2[2] = { bn2[wave * 32 + l15], bn2[wave * 32 + 16 + l15] };
#pragma unroll
    for (int mt = 0; mt < 4; ++mt) {
#pragma unroll
        for (int r = 0; r < 4; ++r) {
            int row = mt * 16 + quad * 4 + r;
            int node = n0 + row;
            if (node < N_NODES) {
#pragma unroll
                for (int nn = 0; nn < 2; ++nn) {
                    int cc = wave * 32 + nn * 16 + l15;
                    out_nodes[(size_t)node * 128 + cc] = acc2[nn][mt][r] + bias2[nn];
                }
            }
        }
    }
}

extern "C" void kernel_launch(void* const* d_in, const int* in_sizes, int n_in,
                              void* d_out, int out_size, void* d_ws, size_t ws_size,
                              hipStream_t stream) {
    const float* x         = (const float*)d_in[0];
    const int*   eidx      = (const int*)d_in[1];
    const float* edge_attr = (const float*)d_in[2];
    const float* We1       = (const float*)d_in[3];
    const float* be1       = (const float*)d_in[4];
    const float* We2       = (const float*)d_in[5];
    const float* be2       = (const float*)d_in[6];
    const float* Wn1       = (const float*)d_in[7];
    const float* bn1       = (const float*)d_in[8];
    const float* Wn2       = (const float*)d_in[9];
    const float* bn2       = (const float*)d_in[10];
    float* out = (float*)d_out;

    char* ws = (char*)d_ws;
    size_t off = 0;
    auto alloc = [&](size_t bytes) {
        void* p = ws + off;
        off += (bytes + 255) & ~(size_t)255;
        return p;
    };
    unsigned short* xb   = (unsigned short*)alloc((size_t)N_NODES * D * 2);
    unsigned short* We1s = (unsigned short*)alloc((size_t)384 * 512 * 2);
    unsigned short* We2s = (unsigned short*)alloc((size_t)512 * 128 * 2);
    unsigned short* Wn1s = (unsigned short*)alloc((size_t)256 * 512 * 2);
    unsigned short* Wn2s = (unsigned short*)alloc((size_t)512 * 128 * 2);
    float*          agg  = (float*)alloc((size_t)N_NODES * D * 4);

    precompute_kernel<<<2724, 256, 0, stream>>>(x, xb, We1, We1s, We2, We2s,
                                                Wn1, Wn1s, Wn2, Wn2s, agg);
    edge_mlp_kernel<<<N_EDGES / 64, 256, 0, stream>>>(
        xb, eidx, edge_attr, We1s, be1, We2s, be2, out + (size_t)N_NODES * D, agg);
    node_mlp_kernel<<<(N_NODES + 63) / 64, 256, 0, stream>>>(
        xb, agg, Wn1s, bn1, Wn2s, bn2, out);
}